// Round 4
// baseline (202.113 us; speedup 1.0000x reference)
//
#include <hip/hip_runtime.h>

// SelfAttentionHead: B=4, T=4096, C=1024, H=64, causal, f32 in/out.
// prep_w -> qkv_proj (LDS-free MFMA GEMM, 1 N-tile/wave, 12288 waves) ->
// vtrans (V -> VT) -> attn (paired q-tiles, 4-way KV split, barrier-free).

typedef short  s16x8 __attribute__((ext_vector_type(8)));
typedef float  f32x4 __attribute__((ext_vector_type(4)));

constexpr int B = 4, T = 4096, C = 1024, H = 64;
constexpr int M = B * T;                    // 16384 tokens
constexpr float LOG2E = 1.44269504088896340736f;

__device__ __forceinline__ unsigned short f2bf(float f) {
    union { float f; unsigned u; } v; v.f = f;
    unsigned r = v.u + 0x7fffu + ((v.u >> 16) & 1u);   // RNE
    return (unsigned short)(r >> 16);
}

__device__ __forceinline__ unsigned cvt_pk_bf16(float lo, float hi) {
    unsigned r;
    asm("v_cvt_pk_bf16_f32 %0, %1, %2" : "=v"(r) : "v"(lo), "v"(hi));
    return r;   // [15:0]=bf16(lo), [31:16]=bf16(hi)
}

// ---------------------------------------------------------------------------
// Kernel 1: Wt[n][k] = W_{n/64}[k][n%64] as bf16.
// ---------------------------------------------------------------------------
__global__ void prep_w(const float* __restrict__ Wq, const float* __restrict__ Wk,
                       const float* __restrict__ Wv, unsigned short* __restrict__ Wt) {
    const int n = blockIdx.x;                       // 0..191
    const float* W = (n < 64) ? Wq : (n < 128 ? Wk : Wv);
    const int col = n & 63;
    for (int k = threadIdx.x; k < C; k += blockDim.x)
        Wt[(size_t)n * C + k] = f2bf(W[(size_t)k * H + col]);
}

// ---------------------------------------------------------------------------
// Kernel 2: fused QKV projection, LDS-free.  M=16384,K=1024,N=192 bf16 MFMA.
// 3072 blocks x 256 thr (4 waves).  Block = 16 rows x 64 cols (col-group
// cg = bid%3); wave w owns one 16-col N-tile.  Consecutive blocks share x
// rows (L1/L2 reuse).  12288 waves -> HW-cap 32 waves/CU.  Q pre-scaled.
// ---------------------------------------------------------------------------
__global__ __launch_bounds__(256) void qkv_proj(
    const float* __restrict__ x, const unsigned short* __restrict__ Wt,
    unsigned short* __restrict__ Q, unsigned short* __restrict__ K,
    unsigned short* __restrict__ V) {
    const int t = threadIdx.x, lane = t & 63, w = t >> 6;
    const int i = lane & 15, g = lane >> 4;
    const int cg = (int)blockIdx.x % 3;
    const int rowbase = ((int)blockIdx.x / 3) * 16;
    const int n0 = cg * 64 + w * 16;                // this wave's N-tile base
    const float* xrow = x + (size_t)(rowbase + i) * C + g * 8;
    const unsigned short* brow = Wt + (size_t)(n0 + i) * C + g * 8;

    f32x4 acc = (f32x4){0.f, 0.f, 0.f, 0.f};

#pragma unroll 4
    for (int kc = 0; kc < C; kc += 32) {
        f32x4 a0 = *(const f32x4*)(xrow + kc);
        f32x4 a1 = *(const f32x4*)(xrow + kc + 4);
        s16x8 bf = *(const s16x8*)(brow + kc);
        union { unsigned u[4]; s16x8 v; } a;
        a.u[0] = cvt_pk_bf16(a0[0], a0[1]);
        a.u[1] = cvt_pk_bf16(a0[2], a0[3]);
        a.u[2] = cvt_pk_bf16(a1[0], a1[1]);
        a.u[3] = cvt_pk_bf16(a1[2], a1[3]);
        acc = __builtin_amdgcn_mfma_f32_16x16x32_bf16(a.v, bf, acc, 0, 0, 0);
    }
    // D layout: col=lane&15, row=4*(lane>>4)+r
    const int n = n0 + i;
#pragma unroll
    for (int r = 0; r < 4; ++r) {
        int row = rowbase + g * 4 + r;
        float val = acc[r];
        if (n < 64)       Q[(size_t)row * H + n]         = f2bf(val * 0.125f);
        else if (n < 128) K[(size_t)row * H + (n - 64)]  = f2bf(val);
        else              V[(size_t)row * H + (n - 128)] = f2bf(val);
    }
}

// ---------------------------------------------------------------------------
// Kernel 3: VT[b][h][t] = V[b][t][h].  256 blocks x 256 thr, 64x64 tiles.
// ---------------------------------------------------------------------------
__global__ __launch_bounds__(256) void vtrans(const unsigned short* __restrict__ V,
                                              unsigned short* __restrict__ VT) {
    __shared__ __align__(16) unsigned short tile[64][72];
    const int b = blockIdx.x >> 6, t0 = (blockIdx.x & 63) * 64;
    const int tid = threadIdx.x;
    {
        int row = tid >> 2, col = (tid & 3) * 16;
        s16x8 v0 = *(const s16x8*)(V + (size_t)(b * T + t0 + row) * H + col);
        s16x8 v1 = *(const s16x8*)(V + (size_t)(b * T + t0 + row) * H + col + 8);
        *(s16x8*)&tile[row][col]     = v0;
        *(s16x8*)&tile[row][col + 8] = v1;
    }
    __syncthreads();
    {
        int h = tid >> 2, tcol = (tid & 3) * 16;
        s16x8 o0, o1;
#pragma unroll
        for (int j = 0; j < 8; ++j) o0[j] = (short)tile[tcol + j][h];
#pragma unroll
        for (int j = 0; j < 8; ++j) o1[j] = (short)tile[tcol + 8 + j][h];
        unsigned short* dst = VT + (size_t)(b * H + h) * T + t0 + tcol;
        *(s16x8*)dst       = o0;
        *(s16x8*)(dst + 8) = o1;
    }
}

// ---------------------------------------------------------------------------
// Kernel 4: causal flash attention.
// 512 blocks x 512 thr (8 waves).  Block = batch b, pair p: group 0 (waves
// 0-3) handles q-tile p, group 1 (waves 4-7) handles q-tile 255-p; within a
// group, wave sp handles KV tiles {sp, sp+4, ...}.  Barrier-free inner loop:
// K/VT fragments direct from global; P via per-wave swizzled LDS.
// Partial (m,l,O) merged across the 4 splits at the end.
// ---------------------------------------------------------------------------
__global__ __launch_bounds__(512, 4) void attn(
    const unsigned short* __restrict__ Qg, const unsigned short* __restrict__ Kg,
    const unsigned short* __restrict__ VTg, float* __restrict__ out) {
    __shared__ __align__(16) unsigned short ps[8][16 * 64];
    __shared__ __align__(16) float Olds[8][16][68];
    __shared__ float mS[8][16], lS[8][16];

    const int t = threadIdx.x, lane = t & 63, w = t >> 6;
    const int grp = w >> 2, sp = w & 3;
    const int p = blockIdx.x & 127, b = blockIdx.x >> 7;
    const int qt = grp ? (255 - p) : p;
    const int q0 = qt * 16;
    const int i = lane & 15, g = lane >> 4;

    const unsigned short* Qrow = Qg + (size_t)(b * T + q0 + i) * H;
    s16x8 aq0 = *(const s16x8*)(Qrow + g * 8);
    s16x8 aq1 = *(const s16x8*)(Qrow + 32 + g * 8);

    f32x4 oacc[4];
#pragma unroll
    for (int nt = 0; nt < 4; ++nt) oacc[nt] = (f32x4){0.f, 0.f, 0.f, 0.f};
    float m_run[4], l_run[4];
#pragma unroll
    for (int r = 0; r < 4; ++r) { m_run[r] = -INFINITY; l_run[r] = 0.f; }

    const int nkv = ((q0 + 15) >> 6) + 1;
    unsigned short* myps = ps[w];
    const unsigned short* Kb  = Kg  + (size_t)b * T * H;
    const unsigned short* Vb  = VTg + (size_t)b * H * T;

    for (int tile = sp; tile < nkv; tile += 4) {
        const int kv = tile * 64;

        // ---- K fragments (B-layout direct from global)
        s16x8 kb[8];
#pragma unroll
        for (int kst = 0; kst < 2; ++kst)
#pragma unroll
            for (int nt = 0; nt < 4; ++nt)
                kb[kst * 4 + nt] = *(const s16x8*)(Kb + (size_t)(kv + nt * 16 + i) * H + kst * 32 + g * 8);

        // ---- S = Q K^T
        f32x4 s[4];
#pragma unroll
        for (int nt = 0; nt < 4; ++nt) s[nt] = (f32x4){0.f, 0.f, 0.f, 0.f};
#pragma unroll
        for (int nt = 0; nt < 4; ++nt)
            s[nt] = __builtin_amdgcn_mfma_f32_16x16x32_bf16(aq0, kb[nt], s[nt], 0, 0, 0);
#pragma unroll
        for (int nt = 0; nt < 4; ++nt)
            s[nt] = __builtin_amdgcn_mfma_f32_16x16x32_bf16(aq1, kb[4 + nt], s[nt], 0, 0, 0);

        // ---- VT fragments for PV (issue early; independent of softmax)
        s16x8 vb[8];
#pragma unroll
        for (int kst = 0; kst < 2; ++kst)
#pragma unroll
            for (int nt = 0; nt < 4; ++nt)
                vb[kst * 4 + nt] = *(const s16x8*)(Vb + (size_t)(nt * 16 + i) * T + kv + kst * 32 + g * 8);

        // ---- causal mask: lane holds q = q0+4g+r, key = kv + nt*16 + i
        const int rq0 = q0 + g * 4;
#pragma unroll
        for (int nt = 0; nt < 4; ++nt) {
            int key = kv + nt * 16 + i;
#pragma unroll
            for (int r = 0; r < 4; ++r)
                if (key > rq0 + r) s[nt][r] = -INFINITY;
        }

        // ---- online softmax (key dim: 4 nt regs + 16-lane groups)
#pragma unroll
        for (int r = 0; r < 4; ++r) {
            float mx = fmaxf(fmaxf(s[0][r], s[1][r]), fmaxf(s[2][r], s[3][r]));
            mx = fmaxf(mx, __shfl_xor(mx, 1));
            mx = fmaxf(mx, __shfl_xor(mx, 2));
            mx = fmaxf(mx, __shfl_xor(mx, 4));
            mx = fmaxf(mx, __shfl_xor(mx, 8));
            float mnew = fmaxf(m_run[r], mx);
            float scale = exp2f((m_run[r] - mnew) * LOG2E);
            float rs = 0.f;
#pragma unroll
            for (int nt = 0; nt < 4; ++nt) {
                float pv = exp2f((s[nt][r] - mnew) * LOG2E);
                s[nt][r] = pv;
                rs += pv;
            }
            rs += __shfl_xor(rs, 1);
            rs += __shfl_xor(rs, 2);
            rs += __shfl_xor(rs, 4);
            rs += __shfl_xor(rs, 8);
            l_run[r] = l_run[r] * scale + rs;
            m_run[r] = mnew;
#pragma unroll
            for (int nt = 0; nt < 4; ++nt) oacc[nt][r] *= scale;
        }

        // ---- P (D-layout) -> per-wave LDS (swizzled) -> A-layout
#pragma unroll
        for (int nt = 0; nt < 4; ++nt) {
            int colk = nt * 16 + i;
#pragma unroll
            for (int r = 0; r < 4; ++r) {
                int row = g * 4 + r;
                myps[row * 64 + (colk ^ ((row & 7) << 3))] = f2bf(s[nt][r]);
            }
        }

        // ---- O += P V
#pragma unroll
        for (int kst = 0; kst < 2; ++kst) {
            s16x8 pa = *(const s16x8*)&myps[i * 64 + ((kst * 32 + g * 8) ^ ((i & 7) << 3))];
#pragma unroll
            for (int nt = 0; nt < 4; ++nt)
                oacc[nt] = __builtin_amdgcn_mfma_f32_16x16x32_bf16(pa, vb[kst * 4 + nt], oacc[nt], 0, 0, 0);
        }
    }

    // ---- write partial (m, l, O) and merge the 4 KV splits
#pragma unroll
    for (int nt = 0; nt < 4; ++nt)
#pragma unroll
        for (int r = 0; r < 4; ++r)
            Olds[w][g * 4 + r][nt * 16 + i] = oacc[nt][r];
    if (i == 0) {
#pragma unroll
        for (int r = 0; r < 4; ++r) { mS[w][g * 4 + r] = m_run[r]; lS[w][g * 4 + r] = l_run[r]; }
    }
    __syncthreads();

    {
        const int grp2 = t >> 8, idx = t & 255;
        const int q = idx >> 4, hc = (idx & 15) * 4;
        const int w0 = grp2 * 4;
        float Mx = fmaxf(fmaxf(mS[w0][q], mS[w0 + 1][q]), fmaxf(mS[w0 + 2][q], mS[w0 + 3][q]));
        float L = 0.f;
        f32x4 o = (f32x4){0.f, 0.f, 0.f, 0.f};
#pragma unroll
        for (int s4 = 0; s4 < 4; ++s4) {
            float wg = exp2f((mS[w0 + s4][q] - Mx) * LOG2E);
            L += wg * lS[w0 + s4][q];
            f32x4 ov = *(const f32x4*)&Olds[w0 + s4][q][hc];
            o[0] += wg * ov[0]; o[1] += wg * ov[1]; o[2] += wg * ov[2]; o[3] += wg * ov[3];
        }
        const int qq = (grp2 ? (255 - p) : p) * 16 + q;
        float inv = 1.0f / L;
        f32x4 res = (f32x4){o[0] * inv, o[1] * inv, o[2] * inv, o[3] * inv};
        *(f32x4*)(out + (size_t)(b * T + qq) * H + hc) = res;
    }
}

// ---------------------------------------------------------------------------
extern "C" void kernel_launch(void* const* d_in, const int* in_sizes, int n_in,
                              void* d_out, int out_size, void* d_ws, size_t ws_size,
                              hipStream_t stream) {
    (void)in_sizes; (void)n_in; (void)out_size; (void)ws_size;
    const float* x  = (const float*)d_in[0];
    const float* Wq = (const float*)d_in[1];
    const float* Wk = (const float*)d_in[2];
    const float* Wv = (const float*)d_in[3];
    float* out = (float*)d_out;

    char* ws = (char*)d_ws;
    unsigned short* Q  = (unsigned short*)(ws);
    unsigned short* K  = (unsigned short*)(ws + (size_t)1 * M * H * 2);
    unsigned short* V  = (unsigned short*)(ws + (size_t)2 * M * H * 2);
    unsigned short* VT = (unsigned short*)(ws + (size_t)3 * M * H * 2);
    unsigned short* Wt = (unsigned short*)(ws + (size_t)4 * M * H * 2);
    // workspace: 4*2MB + 384KB = 8.4MB

    prep_w<<<192, 256, 0, stream>>>(Wq, Wk, Wv, Wt);
    qkv_proj<<<3072, 256, 0, stream>>>(x, Wt, Q, K, V);
    vtrans<<<B * (T / 64), 256, 0, stream>>>(V, VT);
    attn<<<B * 128, 512, 0, stream>>>(Q, K, VT, out);
}

// Round 5
// 98.680 us; speedup vs baseline: 2.0482x; 2.0482x over previous
//
#include <hip/hip_runtime.h>

// SelfAttentionHead: B=4, T=4096, C=1024, H=64, causal, f32 in/out.
// prep_w -> qkv_proj (LDS double-buffered MFMA GEMM, global_load_lds B,
// reg-staged A with issue-early/write-late) -> vtrans -> attn (paired
// q-tiles, 4-way KV split, barrier-free inner loop).

typedef short  s16x8 __attribute__((ext_vector_type(8)));
typedef float  f32x4 __attribute__((ext_vector_type(4)));

constexpr int B = 4, T = 4096, C = 1024, H = 64;
constexpr int M = B * T;                    // 16384 tokens
constexpr float LOG2E = 1.44269504088896340736f;

__device__ __forceinline__ unsigned short f2bf(float f) {
    union { float f; unsigned u; } v; v.f = f;
    unsigned r = v.u + 0x7fffu + ((v.u >> 16) & 1u);   // RNE
    return (unsigned short)(r >> 16);
}

__device__ __forceinline__ unsigned cvt_pk_bf16(float lo, float hi) {
    unsigned r;
    asm("v_cvt_pk_bf16_f32 %0, %1, %2" : "=v"(r) : "v"(lo), "v"(hi));
    return r;   // [15:0]=bf16(lo), [31:16]=bf16(hi)
}

__device__ __forceinline__ void gl_lds16(const void* g, void* l) {
    __builtin_amdgcn_global_load_lds(
        (const __attribute__((address_space(1))) unsigned*)g,
        (__attribute__((address_space(3))) unsigned*)l, 16, 0, 0);
}

// ---------------------------------------------------------------------------
// Kernel 1: Wt[n][k] = W_{n/64}[k][n%64] as bf16.
// ---------------------------------------------------------------------------
__global__ void prep_w(const float* __restrict__ Wq, const float* __restrict__ Wk,
                       const float* __restrict__ Wv, unsigned short* __restrict__ Wt) {
    const int n = blockIdx.x;                       // 0..191
    const float* W = (n < 64) ? Wq : (n < 128 ? Wk : Wv);
    const int col = n & 63;
    for (int k = threadIdx.x; k < C; k += blockDim.x)
        Wt[(size_t)n * C + k] = f2bf(W[(size_t)k * H + col]);
}

// ---------------------------------------------------------------------------
// Kernel 2: fused QKV projection.  M=16384,K=1024,N=192 bf16 MFMA.
// 512 blocks x 256 thr (4 waves).  Tile BM=32 x BN=192, BK=64, double-buffered
// LDS.  Slot convention: LDS row r, 16B slot s holds global k-chunk (s^(r&7))
// -> conflict-free ds_read_b128 (2-way max).  B staged with global_load_lds
// (linear dest, pre-swizzled source); A reg-staged f32->bf16 (issue-early /
// write-late).  Wave w: rows (w&1)*16.., N-half (w>>1)*96.. (6 accumulators).
// Q pre-scaled by 0.125.
// ---------------------------------------------------------------------------
__global__ __launch_bounds__(256) void qkv_proj(
    const float* __restrict__ x, const unsigned short* __restrict__ Wt,
    unsigned short* __restrict__ Q, unsigned short* __restrict__ K,
    unsigned short* __restrict__ V) {
    __shared__ __align__(16) unsigned short ldsA[2][32 * 64];    //  8 KB
    __shared__ __align__(16) unsigned short ldsB[2][192 * 64];   // 48 KB

    const int t = threadIdx.x, lane = t & 63, w = t >> 6;
    const int i = lane & 15, g = lane >> 4;
    const int rowbase = blockIdx.x * 32;
    const int nh = w >> 1, r0 = (w & 1) * 16;

    // A staging map: thread t -> row (t>>3), slot (t&7); loads global chunk slot^(row&7)
    const int arow = t >> 3, aslot = t & 7;
    const float* aga = x + (size_t)(rowbase + arow) * C + ((aslot ^ (arow & 7)) * 8);
    const int awoff = arow * 64 + aslot * 8;

    // B staging map: wave w, instr j -> rows n0=w*48+j*8 (+lane>>3), linear LDS dest
    const int brow8 = lane >> 3, bslot = lane & 7;
    const unsigned short* bga[6];
    int bn0[6];
#pragma unroll
    for (int j = 0; j < 6; ++j) {
        bn0[j] = w * 48 + j * 8;
        bga[j] = Wt + (size_t)(bn0[j] + brow8) * C + ((bslot ^ brow8) * 8);
    }

    f32x4 acc[6];
#pragma unroll
    for (int n = 0; n < 6; ++n) acc[n] = (f32x4){0.f, 0.f, 0.f, 0.f};

    // ---- prologue: stage tile 0 into buf 0
    {
        f32x4 a0 = *(const f32x4*)(aga);
        f32x4 a1 = *(const f32x4*)(aga + 4);
#pragma unroll
        for (int j = 0; j < 6; ++j)
            gl_lds16(bga[j], &ldsB[0][bn0[j] * 64]);
        union { unsigned u[4]; s16x8 v; } av;
        av.u[0] = cvt_pk_bf16(a0[0], a0[1]);
        av.u[1] = cvt_pk_bf16(a0[2], a0[3]);
        av.u[2] = cvt_pk_bf16(a1[0], a1[1]);
        av.u[3] = cvt_pk_bf16(a1[2], a1[3]);
        *(s16x8*)&ldsA[0][awoff] = av.v;
    }
    __syncthreads();

    for (int it = 0; it < 16; ++it) {
        const int cur = it & 1, nxt = cur ^ 1;
        const int kc = (it + 1) * 64;
        f32x4 a0, a1;
        const bool more = (it < 15);
        if (more) {
            // issue next-tile loads: A -> regs (held across compute), B -> LDS async
            a0 = *(const f32x4*)(aga + kc);
            a1 = *(const f32x4*)(aga + kc + 4);
#pragma unroll
            for (int j = 0; j < 6; ++j)
                gl_lds16(bga[j] + kc, &ldsB[nxt][bn0[j] * 64]);
        }
        // ---- compute on buf cur (ds_read + MFMA only)
#pragma unroll
        for (int kst = 0; kst < 2; ++kst) {
            const int c = kst * 4 + g;
            s16x8 a = *(const s16x8*)&ldsA[cur][(r0 + i) * 64 + ((c ^ (i & 7)) * 8)];
#pragma unroll
            for (int nt = 0; nt < 6; ++nt) {
                int n = nh * 96 + nt * 16 + i;            // n&7 == i&7
                s16x8 b = *(const s16x8*)&ldsB[cur][n * 64 + ((c ^ (i & 7)) * 8)];
                acc[nt] = __builtin_amdgcn_mfma_f32_16x16x32_bf16(a, b, acc[nt], 0, 0, 0);
            }
        }
        if (more) {
            // write-late: A regs -> LDS (vmcnt wait hidden under compute above)
            union { unsigned u[4]; s16x8 v; } av;
            av.u[0] = cvt_pk_bf16(a0[0], a0[1]);
            av.u[1] = cvt_pk_bf16(a0[2], a0[3]);
            av.u[2] = cvt_pk_bf16(a1[0], a1[1]);
            av.u[3] = cvt_pk_bf16(a1[2], a1[3]);
            *(s16x8*)&ldsA[nxt][awoff] = av.v;
        }
        __syncthreads();
    }

    // ---- epilogue: D layout col=lane&15, row=4*(lane>>4)+r
#pragma unroll
    for (int nt = 0; nt < 6; ++nt) {
        int n = nh * 96 + nt * 16 + i;
#pragma unroll
        for (int r = 0; r < 4; ++r) {
            int row = rowbase + r0 + g * 4 + r;
            float val = acc[nt][r];
            if (n < 64)       Q[(size_t)row * H + n]         = f2bf(val * 0.125f);
            else if (n < 128) K[(size_t)row * H + (n - 64)]  = f2bf(val);
            else              V[(size_t)row * H + (n - 128)] = f2bf(val);
        }
    }
}

// ---------------------------------------------------------------------------
// Kernel 3: VT[b][h][t] = V[b][t][h].  256 blocks x 256 thr, 64x64 tiles.
// ---------------------------------------------------------------------------
__global__ __launch_bounds__(256) void vtrans(const unsigned short* __restrict__ V,
                                              unsigned short* __restrict__ VT) {
    __shared__ __align__(16) unsigned short tile[64][72];
    const int b = blockIdx.x >> 6, t0 = (blockIdx.x & 63) * 64;
    const int tid = threadIdx.x;
    {
        int row = tid >> 2, col = (tid & 3) * 16;
        s16x8 v0 = *(const s16x8*)(V + (size_t)(b * T + t0 + row) * H + col);
        s16x8 v1 = *(const s16x8*)(V + (size_t)(b * T + t0 + row) * H + col + 8);
        *(s16x8*)&tile[row][col]     = v0;
        *(s16x8*)&tile[row][col + 8] = v1;
    }
    __syncthreads();
    {
        int h = tid >> 2, tcol = (tid & 3) * 16;
        s16x8 o0, o1;
#pragma unroll
        for (int j = 0; j < 8; ++j) o0[j] = (short)tile[tcol + j][h];
#pragma unroll
        for (int j = 0; j < 8; ++j) o1[j] = (short)tile[tcol + 8 + j][h];
        unsigned short* dst = VT + (size_t)(b * H + h) * T + t0 + tcol;
        *(s16x8*)dst       = o0;
        *(s16x8*)(dst + 8) = o1;
    }
}

// ---------------------------------------------------------------------------
// Kernel 4: causal flash attention.
// 512 blocks x 512 thr (8 waves).  Block = batch b, pair p: group 0 (waves
// 0-3) handles q-tile p, group 1 (waves 4-7) handles q-tile 255-p; within a
// group, wave sp handles KV tiles {sp, sp+4, ...}.  Barrier-free inner loop:
// K/VT fragments direct from global; P via per-wave swizzled LDS.
// Partial (m,l,O) merged across the 4 splits at the end.
// ---------------------------------------------------------------------------
__global__ __launch_bounds__(512, 4) void attn(
    const unsigned short* __restrict__ Qg, const unsigned short* __restrict__ Kg,
    const unsigned short* __restrict__ VTg, float* __restrict__ out) {
    __shared__ __align__(16) unsigned short ps[8][16 * 64];
    __shared__ __align__(16) float Olds[8][16][68];
    __shared__ float mS[8][16], lS[8][16];

    const int t = threadIdx.x, lane = t & 63, w = t >> 6;
    const int grp = w >> 2, sp = w & 3;
    const int p = blockIdx.x & 127, b = blockIdx.x >> 7;
    const int qt = grp ? (255 - p) : p;
    const int q0 = qt * 16;
    const int i = lane & 15, g = lane >> 4;

    const unsigned short* Qrow = Qg + (size_t)(b * T + q0 + i) * H;
    s16x8 aq0 = *(const s16x8*)(Qrow + g * 8);
    s16x8 aq1 = *(const s16x8*)(Qrow + 32 + g * 8);

    f32x4 oacc[4];
#pragma unroll
    for (int nt = 0; nt < 4; ++nt) oacc[nt] = (f32x4){0.f, 0.f, 0.f, 0.f};
    float m_run[4], l_run[4];
#pragma unroll
    for (int r = 0; r < 4; ++r) { m_run[r] = -INFINITY; l_run[r] = 0.f; }

    const int nkv = ((q0 + 15) >> 6) + 1;
    unsigned short* myps = ps[w];
    const unsigned short* Kb  = Kg  + (size_t)b * T * H;
    const unsigned short* Vb  = VTg + (size_t)b * H * T;

    for (int tile = sp; tile < nkv; tile += 4) {
        const int kv = tile * 64;

        // ---- K fragments (B-layout direct from global)
        s16x8 kb[8];
#pragma unroll
        for (int kst = 0; kst < 2; ++kst)
#pragma unroll
            for (int nt = 0; nt < 4; ++nt)
                kb[kst * 4 + nt] = *(const s16x8*)(Kb + (size_t)(kv + nt * 16 + i) * H + kst * 32 + g * 8);

        // ---- S = Q K^T
        f32x4 s[4];
#pragma unroll
        for (int nt = 0; nt < 4; ++nt) s[nt] = (f32x4){0.f, 0.f, 0.f, 0.f};
#pragma unroll
        for (int nt = 0; nt < 4; ++nt)
            s[nt] = __builtin_amdgcn_mfma_f32_16x16x32_bf16(aq0, kb[nt], s[nt], 0, 0, 0);
#pragma unroll
        for (int nt = 0; nt < 4; ++nt)
            s[nt] = __builtin_amdgcn_mfma_f32_16x16x32_bf16(aq1, kb[4 + nt], s[nt], 0, 0, 0);

        // ---- VT fragments for PV (issue early; independent of softmax)
        s16x8 vb[8];
#pragma unroll
        for (int kst = 0; kst < 2; ++kst)
#pragma unroll
            for (int nt = 0; nt < 4; ++nt)
                vb[kst * 4 + nt] = *(const s16x8*)(Vb + (size_t)(nt * 16 + i) * T + kv + kst * 32 + g * 8);

        // ---- causal mask: lane holds q = q0+4g+r, key = kv + nt*16 + i
        const int rq0 = q0 + g * 4;
#pragma unroll
        for (int nt = 0; nt < 4; ++nt) {
            int key = kv + nt * 16 + i;
#pragma unroll
            for (int r = 0; r < 4; ++r)
                if (key > rq0 + r) s[nt][r] = -INFINITY;
        }

        // ---- online softmax (key dim: 4 nt regs + 16-lane groups)
#pragma unroll
        for (int r = 0; r < 4; ++r) {
            float mx = fmaxf(fmaxf(s[0][r], s[1][r]), fmaxf(s[2][r], s[3][r]));
            mx = fmaxf(mx, __shfl_xor(mx, 1));
            mx = fmaxf(mx, __shfl_xor(mx, 2));
            mx = fmaxf(mx, __shfl_xor(mx, 4));
            mx = fmaxf(mx, __shfl_xor(mx, 8));
            float mnew = fmaxf(m_run[r], mx);
            float scale = exp2f((m_run[r] - mnew) * LOG2E);
            float rs = 0.f;
#pragma unroll
            for (int nt = 0; nt < 4; ++nt) {
                float pv = exp2f((s[nt][r] - mnew) * LOG2E);
                s[nt][r] = pv;
                rs += pv;
            }
            rs += __shfl_xor(rs, 1);
            rs += __shfl_xor(rs, 2);
            rs += __shfl_xor(rs, 4);
            rs += __shfl_xor(rs, 8);
            l_run[r] = l_run[r] * scale + rs;
            m_run[r] = mnew;
#pragma unroll
            for (int nt = 0; nt < 4; ++nt) oacc[nt][r] *= scale;
        }

        // ---- P (D-layout) -> per-wave LDS (swizzled) -> A-layout
#pragma unroll
        for (int nt = 0; nt < 4; ++nt) {
            int colk = nt * 16 + i;
#pragma unroll
            for (int r = 0; r < 4; ++r) {
                int row = g * 4 + r;
                myps[row * 64 + (colk ^ ((row & 7) << 3))] = f2bf(s[nt][r]);
            }
        }

        // ---- O += P V
#pragma unroll
        for (int kst = 0; kst < 2; ++kst) {
            s16x8 pa = *(const s16x8*)&myps[i * 64 + ((kst * 32 + g * 8) ^ ((i & 7) << 3))];
#pragma unroll
            for (int nt = 0; nt < 4; ++nt)
                oacc[nt] = __builtin_amdgcn_mfma_f32_16x16x32_bf16(pa, vb[kst * 4 + nt], oacc[nt], 0, 0, 0);
        }
    }

    // ---- write partial (m, l, O) and merge the 4 KV splits
#pragma unroll
    for (int nt = 0; nt < 4; ++nt)
#pragma unroll
        for (int r = 0; r < 4; ++r)
            Olds[w][g * 4 + r][nt * 16 + i] = oacc[nt][r];
    if (i == 0) {
#pragma unroll
        for (int r = 0; r < 4; ++r) { mS[w][g * 4 + r] = m_run[r]; lS[w][g * 4 + r] = l_run[r]; }
    }
    __syncthreads();

    {
        const int grp2 = t >> 8, idx = t & 255;
        const int q = idx >> 4, hc = (idx & 15) * 4;
        const int w0 = grp2 * 4;
        float Mx = fmaxf(fmaxf(mS[w0][q], mS[w0 + 1][q]), fmaxf(mS[w0 + 2][q], mS[w0 + 3][q]));
        float L = 0.f;
        f32x4 o = (f32x4){0.f, 0.f, 0.f, 0.f};
#pragma unroll
        for (int s4 = 0; s4 < 4; ++s4) {
            float wg = exp2f((mS[w0 + s4][q] - Mx) * LOG2E);
            L += wg * lS[w0 + s4][q];
            f32x4 ov = *(const f32x4*)&Olds[w0 + s4][q][hc];
            o[0] += wg * ov[0]; o[1] += wg * ov[1]; o[2] += wg * ov[2]; o[3] += wg * ov[3];
        }
        const int qq = (grp2 ? (255 - p) : p) * 16 + q;
        float inv = 1.0f / L;
        f32x4 res = (f32x4){o[0] * inv, o[1] * inv, o[2] * inv, o[3] * inv};
        *(f32x4*)(out + (size_t)(b * T + qq) * H + hc) = res;
    }
}

// ---------------------------------------------------------------------------
extern "C" void kernel_launch(void* const* d_in, const int* in_sizes, int n_in,
                              void* d_out, int out_size, void* d_ws, size_t ws_size,
                              hipStream_t stream) {
    (void)in_sizes; (void)n_in; (void)out_size; (void)ws_size;
    const float* x  = (const float*)d_in[0];
    const float* Wq = (const float*)d_in[1];
    const float* Wk = (const float*)d_in[2];
    const float* Wv = (const float*)d_in[3];
    float* out = (float*)d_out;

    char* ws = (char*)d_ws;
    unsigned short* Q  = (unsigned short*)(ws);
    unsigned short* K  = (unsigned short*)(ws + (size_t)1 * M * H * 2);
    unsigned short* V  = (unsigned short*)(ws + (size_t)2 * M * H * 2);
    unsigned short* VT = (unsigned short*)(ws + (size_t)3 * M * H * 2);
    unsigned short* Wt = (unsigned short*)(ws + (size_t)4 * M * H * 2);
    // workspace: 4*2MB + 384KB = 8.4MB

    prep_w<<<192, 256, 0, stream>>>(Wq, Wk, Wv, Wt);
    qkv_proj<<<M / 32, 256, 0, stream>>>(x, Wt, Q, K, V);
    vtrans<<<B * (T / 64), 256, 0, stream>>>(V, VT);
    attn<<<B * 128, 512, 0, stream>>>(Q, K, VT, out);
}

// Round 6
// 95.366 us; speedup vs baseline: 2.1193x; 1.0347x over previous
//
#include <hip/hip_runtime.h>

// SelfAttentionHead: B=4, T=4096, C=1024, H=64, causal, f32 in/out.
// prep_w -> qkv_proj (LDS double-buffered MFMA GEMM) -> vtrans (V -> VTp,
// key-permuted transpose) -> attn (swapped QK^T, in-register softmax,
// zero-shuffle PV via permuted V, 4-way KV split, paired q-tiles).

typedef short  s16x8 __attribute__((ext_vector_type(8)));
typedef float  f32x4 __attribute__((ext_vector_type(4)));

constexpr int B = 4, T = 4096, C = 1024, H = 64;
constexpr int M = B * T;                    // 16384 tokens
constexpr float LOG2E = 1.44269504088896340736f;

__device__ __forceinline__ unsigned short f2bf(float f) {
    union { float f; unsigned u; } v; v.f = f;
    unsigned r = v.u + 0x7fffu + ((v.u >> 16) & 1u);   // RNE
    return (unsigned short)(r >> 16);
}

__device__ __forceinline__ unsigned cvt_pk_bf16(float lo, float hi) {
    unsigned r;
    asm("v_cvt_pk_bf16_f32 %0, %1, %2" : "=v"(r) : "v"(lo), "v"(hi));
    return r;   // [15:0]=bf16(lo), [31:16]=bf16(hi)
}

__device__ __forceinline__ void gl_lds16(const void* g, void* l) {
    __builtin_amdgcn_global_load_lds(
        (const __attribute__((address_space(1))) unsigned*)g,
        (__attribute__((address_space(3))) unsigned*)l, 16, 0, 0);
}

// ---------------------------------------------------------------------------
// Kernel 1: Wt[n][k] = W_{n/64}[k][n%64] as bf16.
// ---------------------------------------------------------------------------
__global__ void prep_w(const float* __restrict__ Wq, const float* __restrict__ Wk,
                       const float* __restrict__ Wv, unsigned short* __restrict__ Wt) {
    const int n = blockIdx.x;                       // 0..191
    const float* W = (n < 64) ? Wq : (n < 128 ? Wk : Wv);
    const int col = n & 63;
    for (int k = threadIdx.x; k < C; k += blockDim.x)
        Wt[(size_t)n * C + k] = f2bf(W[(size_t)k * H + col]);
}

// ---------------------------------------------------------------------------
// Kernel 2: fused QKV projection.  M=16384,K=1024,N=192 bf16 MFMA.
// 512 blocks x 256 thr (4 waves).  Tile BM=32 x BN=192, BK=64, double-buffered
// LDS.  B staged with global_load_lds (linear dest, pre-swizzled source);
// A reg-staged f32->bf16 (issue-early / write-late).  Q pre-scaled by 0.125.
// ---------------------------------------------------------------------------
__global__ __launch_bounds__(256) void qkv_proj(
    const float* __restrict__ x, const unsigned short* __restrict__ Wt,
    unsigned short* __restrict__ Q, unsigned short* __restrict__ K,
    unsigned short* __restrict__ V) {
    __shared__ __align__(16) unsigned short ldsA[2][32 * 64];    //  8 KB
    __shared__ __align__(16) unsigned short ldsB[2][192 * 64];   // 48 KB

    const int t = threadIdx.x, lane = t & 63, w = t >> 6;
    const int i = lane & 15, g = lane >> 4;
    const int rowbase = blockIdx.x * 32;
    const int nh = w >> 1, r0 = (w & 1) * 16;

    const int arow = t >> 3, aslot = t & 7;
    const float* aga = x + (size_t)(rowbase + arow) * C + ((aslot ^ (arow & 7)) * 8);
    const int awoff = arow * 64 + aslot * 8;

    const int brow8 = lane >> 3, bslot = lane & 7;
    const unsigned short* bga[6];
    int bn0[6];
#pragma unroll
    for (int j = 0; j < 6; ++j) {
        bn0[j] = w * 48 + j * 8;
        bga[j] = Wt + (size_t)(bn0[j] + brow8) * C + ((bslot ^ brow8) * 8);
    }

    f32x4 acc[6];
#pragma unroll
    for (int n = 0; n < 6; ++n) acc[n] = (f32x4){0.f, 0.f, 0.f, 0.f};

    {
        f32x4 a0 = *(const f32x4*)(aga);
        f32x4 a1 = *(const f32x4*)(aga + 4);
#pragma unroll
        for (int j = 0; j < 6; ++j)
            gl_lds16(bga[j], &ldsB[0][bn0[j] * 64]);
        union { unsigned u[4]; s16x8 v; } av;
        av.u[0] = cvt_pk_bf16(a0[0], a0[1]);
        av.u[1] = cvt_pk_bf16(a0[2], a0[3]);
        av.u[2] = cvt_pk_bf16(a1[0], a1[1]);
        av.u[3] = cvt_pk_bf16(a1[2], a1[3]);
        *(s16x8*)&ldsA[0][awoff] = av.v;
    }
    __syncthreads();

    for (int it = 0; it < 16; ++it) {
        const int cur = it & 1, nxt = cur ^ 1;
        const int kc = (it + 1) * 64;
        f32x4 a0, a1;
        const bool more = (it < 15);
        if (more) {
            a0 = *(const f32x4*)(aga + kc);
            a1 = *(const f32x4*)(aga + kc + 4);
#pragma unroll
            for (int j = 0; j < 6; ++j)
                gl_lds16(bga[j] + kc, &ldsB[nxt][bn0[j] * 64]);
        }
#pragma unroll
        for (int kst = 0; kst < 2; ++kst) {
            const int c = kst * 4 + g;
            s16x8 a = *(const s16x8*)&ldsA[cur][(r0 + i) * 64 + ((c ^ (i & 7)) * 8)];
#pragma unroll
            for (int nt = 0; nt < 6; ++nt) {
                int n = nh * 96 + nt * 16 + i;
                s16x8 b = *(const s16x8*)&ldsB[cur][n * 64 + ((c ^ (i & 7)) * 8)];
                acc[nt] = __builtin_amdgcn_mfma_f32_16x16x32_bf16(a, b, acc[nt], 0, 0, 0);
            }
        }
        if (more) {
            union { unsigned u[4]; s16x8 v; } av;
            av.u[0] = cvt_pk_bf16(a0[0], a0[1]);
            av.u[1] = cvt_pk_bf16(a0[2], a0[3]);
            av.u[2] = cvt_pk_bf16(a1[0], a1[1]);
            av.u[3] = cvt_pk_bf16(a1[2], a1[3]);
            *(s16x8*)&ldsA[nxt][awoff] = av.v;
        }
        __syncthreads();
    }

#pragma unroll
    for (int nt = 0; nt < 6; ++nt) {
        int n = nh * 96 + nt * 16 + i;
#pragma unroll
        for (int r = 0; r < 4; ++r) {
            int row = rowbase + r0 + g * 4 + r;
            float val = acc[nt][r];
            if (n < 64)       Q[(size_t)row * H + n]         = f2bf(val * 0.125f);
            else if (n < 128) K[(size_t)row * H + (n - 64)]  = f2bf(val);
            else              V[(size_t)row * H + (n - 128)] = f2bf(val);
        }
    }
}

// ---------------------------------------------------------------------------
// Kernel 3: VTp[b][h][t'] = V[b][perm(t')][h], key-permuted transpose.
// Within each 32-token block, position p holds token ((p>>2)&1)*16 +
// (p>>3)*4 + (p&3) -- so attn's packed-P registers are directly a valid
// PV B-fragment (zero shuffles).  256 blocks x 256 thr, 64x64 tiles.
// ---------------------------------------------------------------------------
__global__ __launch_bounds__(256) void vtrans(const unsigned short* __restrict__ V,
                                              unsigned short* __restrict__ VT) {
    __shared__ __align__(16) unsigned short tile[64][72];
    const int b = blockIdx.x >> 6, t0 = (blockIdx.x & 63) * 64;
    const int tid = threadIdx.x;
    {
        int row = tid >> 2, col = (tid & 3) * 16;
        s16x8 v0 = *(const s16x8*)(V + (size_t)(b * T + t0 + row) * H + col);
        s16x8 v1 = *(const s16x8*)(V + (size_t)(b * T + t0 + row) * H + col + 8);
        *(s16x8*)&tile[row][col]     = v0;
        *(s16x8*)&tile[row][col + 8] = v1;
    }
    __syncthreads();
    {
        int h = tid >> 2, tcol = (tid & 3) * 16;
        s16x8 o0, o1;
#pragma unroll
        for (int j = 0; j < 8; ++j) {
            int pos = tcol + j, c = pos >> 5, pp = pos & 31;
            int tok = (c << 5) | (((pp >> 2) & 1) << 4) | ((pp >> 3) << 2) | (pp & 3);
            o0[j] = (short)tile[tok][h];
        }
#pragma unroll
        for (int j = 0; j < 8; ++j) {
            int pos = tcol + 8 + j, c = pos >> 5, pp = pos & 31;
            int tok = (c << 5) | (((pp >> 2) & 1) << 4) | ((pp >> 3) << 2) | (pp & 3);
            o1[j] = (short)tile[tok][h];
        }
        unsigned short* dst = VT + (size_t)(b * H + h) * T + t0 + tcol;
        *(s16x8*)dst       = o0;
        *(s16x8*)(dst + 8) = o1;
    }
}

// ---------------------------------------------------------------------------
// Kernel 4: causal flash attention, swapped-QK^T form.
// 512 blocks x 512 thr (8 waves); block = batch b, pair p: waves 0-3 work
// q-tile p, waves 4-7 work q-tile 255-p; wave sp takes KV tiles {sp,sp+4,..}.
// S^T = mfma(K, Q): lane owns q = q0+(lane&15), keys 16nt+4g+r in-register.
// Softmax: in-lane trees + 2 shfl.  P packs via cvt_pk straight into a PV
// B-fragment (V key-permuted by vtrans).  No LDS in the loop, no P round-trip.
// Partial (m,l,O) merged across the 4 splits at the end.
// ---------------------------------------------------------------------------
__global__ __launch_bounds__(512, 4) void attn(
    const unsigned short* __restrict__ Qg, const unsigned short* __restrict__ Kg,
    const unsigned short* __restrict__ VTg, float* __restrict__ out) {
    __shared__ __align__(16) float Olds[8][16][68];
    __shared__ float mS[8][16], lS[8][16];

    const int t = threadIdx.x, lane = t & 63, w = t >> 6;
    const int grp = w >> 2, sp = w & 3;
    const int p = blockIdx.x & 127, b = blockIdx.x >> 7;
    const int qt = grp ? (255 - p) : p;
    const int q0 = qt * 16;
    const int i = lane & 15, g = lane >> 4, g4 = g * 4;

    // Q as B-fragment: col=i=q, k=h
    const unsigned short* Qrow = Qg + (size_t)(b * T + q0 + i) * H;
    s16x8 bq0 = *(const s16x8*)(Qrow + g * 8);
    s16x8 bq1 = *(const s16x8*)(Qrow + 32 + g * 8);

    // O^T accumulators: oacc[nt4][r] = O[q0+i][h=16*nt4+4g+r]
    f32x4 oacc[4];
#pragma unroll
    for (int nt = 0; nt < 4; ++nt) oacc[nt] = (f32x4){0.f, 0.f, 0.f, 0.f};
    float m_run = -INFINITY, l_run = 0.f;

    const int nkv = ((q0 + 15) >> 6) + 1;
    const unsigned short* Kb = Kg  + (size_t)b * T * H;
    const unsigned short* Vb = VTg + (size_t)b * H * T;

    for (int tile = sp; tile < nkv; tile += 4) {
        const int kv = tile * 64;

        // ---- K as A-fragments (row=i=key, k=h); direct 16B loads
        s16x8 kb[8];
#pragma unroll
        for (int kst = 0; kst < 2; ++kst)
#pragma unroll
            for (int nt = 0; nt < 4; ++nt)
                kb[kst * 4 + nt] = *(const s16x8*)(Kb + (size_t)(kv + nt * 16 + i) * H + kst * 32 + g * 8);

        // ---- S^T = K Q^T : s[nt][r] = S[q0+i][kv+16nt+4g+r]
        f32x4 s[4];
#pragma unroll
        for (int nt = 0; nt < 4; ++nt) s[nt] = (f32x4){0.f, 0.f, 0.f, 0.f};
#pragma unroll
        for (int nt = 0; nt < 4; ++nt)
            s[nt] = __builtin_amdgcn_mfma_f32_16x16x32_bf16(kb[nt], bq0, s[nt], 0, 0, 0);
#pragma unroll
        for (int nt = 0; nt < 4; ++nt)
            s[nt] = __builtin_amdgcn_mfma_f32_16x16x32_bf16(kb[4 + nt], bq1, s[nt], 0, 0, 0);

        // ---- V^T A-fragments (permuted layout); issue early, used after softmax
        s16x8 vb[8];
#pragma unroll
        for (int kst = 0; kst < 2; ++kst)
#pragma unroll
            for (int nt = 0; nt < 4; ++nt)
                vb[kst * 4 + nt] = *(const s16x8*)(Vb + (size_t)(nt * 16 + i) * T + kv + kst * 32 + g * 8);

        // ---- causal mask (skip for fully-causal tiles; wave-uniform branch)
        if (kv + 63 > q0) {
            const int thr = q0 + i - kv;
#pragma unroll
            for (int nt = 0; nt < 4; ++nt)
#pragma unroll
                for (int r = 0; r < 4; ++r)
                    if (nt * 16 + g4 + r > thr) s[nt][r] = -INFINITY;
        }

        // ---- in-lane softmax over 16 keys + 2-shfl cross-group reduce
        float mx = fmaxf(
            fmaxf(fmaxf(fmaxf(s[0][0], s[0][1]), fmaxf(s[0][2], s[0][3])),
                  fmaxf(fmaxf(s[1][0], s[1][1]), fmaxf(s[1][2], s[1][3]))),
            fmaxf(fmaxf(fmaxf(s[2][0], s[2][1]), fmaxf(s[2][2], s[2][3])),
                  fmaxf(fmaxf(s[3][0], s[3][1]), fmaxf(s[3][2], s[3][3]))));
        mx = fmaxf(mx, __shfl_xor(mx, 16));
        mx = fmaxf(mx, __shfl_xor(mx, 32));
        const float mnew = fmaxf(m_run, mx);
        const float mL = mnew * LOG2E;
        const float scale = exp2f(m_run * LOG2E - mL);
#pragma unroll
        for (int nt = 0; nt < 4; ++nt)
#pragma unroll
            for (int r = 0; r < 4; ++r)
                s[nt][r] = exp2f(s[nt][r] * LOG2E - mL);
        float rs = ((s[0][0] + s[0][1]) + (s[0][2] + s[0][3]))
                 + ((s[1][0] + s[1][1]) + (s[1][2] + s[1][3]))
                 + ((s[2][0] + s[2][1]) + (s[2][2] + s[2][3]))
                 + ((s[3][0] + s[3][1]) + (s[3][2] + s[3][3]));
        rs += __shfl_xor(rs, 16);
        rs += __shfl_xor(rs, 32);
        l_run = l_run * scale + rs;
        m_run = mnew;
#pragma unroll
        for (int nt = 0; nt < 4; ++nt) {
            oacc[nt][0] *= scale; oacc[nt][1] *= scale;
            oacc[nt][2] *= scale; oacc[nt][3] *= scale;
        }

        // ---- pack P to bf16; pk[4*kst..4*kst+3] IS the PV B-fragment
        unsigned pk[8];
#pragma unroll
        for (int nt = 0; nt < 4; ++nt) {
            pk[nt * 2]     = cvt_pk_bf16(s[nt][0], s[nt][1]);
            pk[nt * 2 + 1] = cvt_pk_bf16(s[nt][2], s[nt][3]);
        }

        // ---- O^T += V^T P^T
#pragma unroll
        for (int kst = 0; kst < 2; ++kst) {
            union { unsigned u[4]; s16x8 v; } pb;
            pb.u[0] = pk[4 * kst];     pb.u[1] = pk[4 * kst + 1];
            pb.u[2] = pk[4 * kst + 2]; pb.u[3] = pk[4 * kst + 3];
#pragma unroll
            for (int nt = 0; nt < 4; ++nt)
                oacc[nt] = __builtin_amdgcn_mfma_f32_16x16x32_bf16(vb[kst * 4 + nt], pb.v, oacc[nt], 0, 0, 0);
        }
    }

    // ---- write partial (m, l, O^T) and merge the 4 KV splits
#pragma unroll
    for (int nt = 0; nt < 4; ++nt)
#pragma unroll
        for (int r = 0; r < 4; ++r)
            Olds[w][i][nt * 16 + g4 + r] = oacc[nt][r];
    if (g == 0) { mS[w][i] = m_run; lS[w][i] = l_run; }
    __syncthreads();

    {
        const int grp2 = t >> 8, idx = t & 255;
        const int q = idx >> 4, hc = (idx & 15) * 4;
        const int w0 = grp2 * 4;
        float Mx = fmaxf(fmaxf(mS[w0][q], mS[w0 + 1][q]), fmaxf(mS[w0 + 2][q], mS[w0 + 3][q]));
        float L = 0.f;
        f32x4 o = (f32x4){0.f, 0.f, 0.f, 0.f};
#pragma unroll
        for (int s4 = 0; s4 < 4; ++s4) {
            float wg = exp2f((mS[w0 + s4][q] - Mx) * LOG2E);
            L += wg * lS[w0 + s4][q];
            f32x4 ov = *(const f32x4*)&Olds[w0 + s4][q][hc];
            o[0] += wg * ov[0]; o[1] += wg * ov[1]; o[2] += wg * ov[2]; o[3] += wg * ov[3];
        }
        const int qq = (grp2 ? (255 - p) : p) * 16 + q;
        float inv = 1.0f / L;
        f32x4 res = (f32x4){o[0] * inv, o[1] * inv, o[2] * inv, o[3] * inv};
        *(f32x4*)(out + (size_t)(b * T + qq) * H + hc) = res;
    }
}

// ---------------------------------------------------------------------------
extern "C" void kernel_launch(void* const* d_in, const int* in_sizes, int n_in,
                              void* d_out, int out_size, void* d_ws, size_t ws_size,
                              hipStream_t stream) {
    (void)in_sizes; (void)n_in; (void)out_size; (void)ws_size;
    const float* x  = (const float*)d_in[0];
    const float* Wq = (const float*)d_in[1];
    const float* Wk = (const float*)d_in[2];
    const float* Wv = (const float*)d_in[3];
    float* out = (float*)d_out;

    char* ws = (char*)d_ws;
    unsigned short* Q  = (unsigned short*)(ws);
    unsigned short* K  = (unsigned short*)(ws + (size_t)1 * M * H * 2);
    unsigned short* V  = (unsigned short*)(ws + (size_t)2 * M * H * 2);
    unsigned short* VT = (unsigned short*)(ws + (size_t)3 * M * H * 2);
    unsigned short* Wt = (unsigned short*)(ws + (size_t)4 * M * H * 2);
    // workspace: 4*2MB + 384KB = 8.4MB

    prep_w<<<192, 256, 0, stream>>>(Wq, Wk, Wv, Wt);
    qkv_proj<<<M / 32, 256, 0, stream>>>(x, Wt, Q, K, V);
    vtrans<<<B * (T / 64), 256, 0, stream>>>(V, VT);
    attn<<<B * 128, 512, 0, stream>>>(Q, K, VT, out);
}